// Round 4
// baseline (317.567 us; speedup 1.0000x reference)
//
#include <hip/hip_runtime.h>
#include <stdint.h>

// VectorQuantizer on MI355X (gfx950) — round 10
// inputs: x [64,256,32,32] fp32 (NCHW), codebook [1024,256] fp32
// outputs: q_st [64,256,32,32] fp32, loss scalar
//
// R10 = R6 (78 us vq_main, the best) + two TLP/ILP levers, nothing else:
//  (1) __launch_bounds__(256,4): LDS 34.3KB allows 4 blocks/CU; R6 asked for 3.
//      12 -> 16 waves/CU of latency-hiding (R7/R8/R9 proved source-level
//      pipelining loses to wave-level overlap on this chip: 111/124/225 us).
//  (2) accumulator split into two 8-deep MFMA chains (c0=nh-init, c1=0-init,
//      one add at scan): doubles per-wave MFMA ILP for +16 VGPR (60->~80,
//      under the 128 cap, no spill).
// Dispatch fold kept from R8/R9 (prep zeroes accum/ticket, last main block
// writes the loss): 2 dispatches total.

#define DIM 256

typedef __attribute__((ext_vector_type(8)))  short bf16x8_t;   // MFMA A/B frag (4 VGPRs)
typedef __attribute__((ext_vector_type(4)))  float f32x4_t;
typedef __attribute__((ext_vector_type(16))) float f32x16_t;   // 32x32 C/D frag

__device__ __forceinline__ uint32_t f2bf(float f) {
    union { float f; uint32_t u; } v; v.f = f;
    uint32_t r = v.u + 0x7FFFu + ((v.u >> 16) & 1u);   // RNE
    return r >> 16;
}

// ---- prep: one wave per code. Emits (a) bf16 codebook in exact MFMA A-frag
// order: entry e=(mt*16+ks)*64+lane2 holds cb[mt*32+(lane2&31)][ks*16+(lane2>>5)*8+j],
// and (b) -0.5*||c||^2 in C/D-register order (nh_ord[mt*32 + half*16 + r]).
// Also zeroes loss_accum and the completion ticket (re-zeroed every replay).
__global__ __launch_bounds__(256) void vq_prep(const float* __restrict__ cb,
                                               char* __restrict__ cbsw,
                                               float* __restrict__ nh_ord,
                                               float* __restrict__ loss_accum,
                                               unsigned* __restrict__ done) {
    if (blockIdx.x == 0 && threadIdx.x == 0) { *loss_accum = 0.f; *done = 0u; }

    const int code = blockIdx.x * 4 + (threadIdx.x >> 6);
    const int l    = threadIdx.x & 63;               // holds d = 4l..4l+3
    const f32x4_t v = ((const f32x4_t*)(cb + code * DIM))[l];
    float sq = v.x * v.x + v.y * v.y + v.z * v.z + v.w * v.w;

    const int mt = code >> 5;
    const int ks = l >> 2;               // d/16
    const int hl = (l >> 1) & 1;         // (d%16)/8
    const uint32_t ebyte = (uint32_t)(((mt * 16 + ks) * 64 + (code & 31) + 32 * hl) * 16
                                      + (l & 1) * 8);
    uint2 o;
    o.x = f2bf(v.x) | (f2bf(v.y) << 16);
    o.y = f2bf(v.z) | (f2bf(v.w) << 16);
    *(uint2*)(cbsw + ebyte) = o;

    #pragma unroll
    for (int m = 32; m; m >>= 1) sq += __shfl_xor(sq, m);
    if (l == 0) {
        const int rw = code & 31;
        const int h4 = (rw >> 2) & 1;
        const int r  = (rw & 3) | ((rw >> 3) << 2);
        nh_ord[mt * 32 + h4 * 16 + r] = -0.5f * sq;
    }
}

// ---- main: 1024 blocks x 256 threads; block = 64 hw rows.
// LDS xt entry E=(ks*2+half)*64+row holds x[row][ks*16+half*8 .. +7] as 8 bf16 (16 B).
// Wave w: n-tile nt=w&1 (rows nt*32..), code-half ch=w>>1 (codes ch*512..).
__global__ __launch_bounds__(256, 4) void vq_main(const float* __restrict__ x,
                                                  const float* __restrict__ cb,
                                                  const bf16x8_t* __restrict__ cbsw,
                                                  const float* __restrict__ nh_ord,
                                                  float* __restrict__ out,
                                                  float* __restrict__ loss_accum,
                                                  unsigned* __restrict__ done) {
    __shared__ uint32_t xt[16 * 2 * 64 * 4];   // 32 KB, B-frag order
    __shared__ float smin[2][64];
    __shared__ int   sidx[2][64];
    __shared__ float sxsq[4];
    __shared__ int   sfin[64];

    const int t     = threadIdx.x;
    const int w     = t >> 6;
    const int lane  = t & 63;
    const int n0    = blockIdx.x * 64;
    const int batch = n0 >> 10;
    const int hw0   = n0 & 1023;

    // ---- stage x -> LDS in fragment order (conflict-free b128 writes) + ||x||^2
    {
        const int col = t & 63;          // hw row within block
        const int oct = t >> 6;          // 0..3: d-octet selector
        const float* xp = x + (size_t)batch * (DIM * 1024) + hw0 + col;
        float sq = 0.f;
        #pragma unroll
        for (int i = 0; i < 8; ++i) {
            const int d0 = oct * 8 + i * 32;     // 8 consecutive d, one LDS entry
            float a[8];
            #pragma unroll
            for (int j = 0; j < 8; ++j) {
                a[j] = xp[(size_t)(d0 + j) * 1024];
                sq += a[j] * a[j];
            }
            uint4 pk;
            pk.x = f2bf(a[0]) | (f2bf(a[1]) << 16);
            pk.y = f2bf(a[2]) | (f2bf(a[3]) << 16);
            pk.z = f2bf(a[4]) | (f2bf(a[5]) << 16);
            pk.w = f2bf(a[6]) | (f2bf(a[7]) << 16);
            const int ks   = d0 >> 4;
            const int half = (d0 >> 3) & 1;
            *(uint4*)&xt[(ks * 512) + (half * 256) + col * 4] = pk;
        }
        // wave-level ||x||^2 partial (all 256 threads cover every (row,d) once)
        #pragma unroll
        for (int m = 32; m; m >>= 1) sq += __shfl_xor(sq, m);
        if (lane == 0) sxsq[w] = sq;
    }
    __syncthreads();

    // ---- K-loop: wave's 512 codes (16 m-tiles); argmax(dot - 0.5*||c||^2)
    const int nt   = w & 1;
    const int ch   = w >> 1;
    const int half = lane >> 5;
    const int col  = lane & 31;
    const uint32_t* xbase = xt + half * 256 + (nt * 32 + col) * 4;

    float best = -3.0e38f;
    int   bi = 0;
    for (int i = 0; i < 16; ++i) {
        const int mt = ch * 16 + i;

        // batch-prefetch all 16 A-frags of this m-tile (16 independent
        // global_load_dwordx4 issued before any MFMA consumes them)
        bf16x8_t apre[16];
        {
            const bf16x8_t* ap = cbsw + mt * (16 * 64) + lane;
            #pragma unroll
            for (int ks = 0; ks < 16; ++ks) apre[ks] = ap[ks * 64];
        }

        const f32x4_t* nhp = (const f32x4_t*)(nh_ord + mt * 32 + half * 16);
        const f32x4_t h0 = nhp[0], h1 = nhp[1], h2 = nhp[2], h3 = nhp[3];

        // two independent 8-deep MFMA chains: c0 starts at -0.5||c||^2, c1 at 0
        f32x16_t c0, c1;
        #pragma unroll
        for (int r = 0; r < 4; ++r) {
            c0[r] = h0[r]; c0[4 + r] = h1[r]; c0[8 + r] = h2[r]; c0[12 + r] = h3[r];
            c1[r] = 0.f;   c1[4 + r] = 0.f;   c1[8 + r] = 0.f;   c1[12 + r] = 0.f;
        }
        #pragma unroll
        for (int ks = 0; ks < 8; ++ks) {
            const bf16x8_t b = *(const bf16x8_t*)(xbase + ks * 512);
            c0 = __builtin_amdgcn_mfma_f32_32x32x16_bf16(apre[ks], b, c0, 0, 0, 0);
        }
        #pragma unroll
        for (int ks = 8; ks < 16; ++ks) {
            const bf16x8_t b = *(const bf16x8_t*)(xbase + ks * 512);
            c1 = __builtin_amdgcn_mfma_f32_32x32x16_bf16(apre[ks], b, c1, 0, 0, 0);
        }

        // scan: codes visited in increasing order; strict > keeps lowest index
        #pragma unroll
        for (int r = 0; r < 16; ++r) {
            const float v = c0[r] + c1[r];
            const int code = mt * 32 + half * 4 + ((r & 3) + 8 * (r >> 2));
            if (v > best) { best = v; bi = code; }
        }
    }

    // ---- combine the two k-half lanes (same hw row, disjoint code subsets)
    {
        const float ov = __shfl_xor(best, 32);
        const int   oi = __shfl_xor(bi, 32);
        if (ov > best || (ov == best && oi < bi)) { best = ov; bi = oi; }
    }
    if (lane < 32) {
        smin[ch][nt * 32 + lane] = best;
        sidx[ch][nt * 32 + lane] = bi;
    }
    __syncthreads();

    // ---- wave 0: combine code halves per row, loss partial, publish indices
    if (w == 0) {
        float b0 = smin[0][lane]; int i0 = sidx[0][lane];
        const float b1 = smin[1][lane]; const int i1 = sidx[1][lane];
        if (b1 > b0) { b0 = b1; i0 = i1; }
        sfin[lane] = i0;
        float ls = -2.f * b0;
        #pragma unroll
        for (int m = 32; m; m >>= 1) ls += __shfl_xor(ls, m);
        if (lane == 0)
            atomicAdd(loss_accum, ls + sxsq[0] + sxsq[1] + sxsq[2] + sxsq[3]);
    }
    __syncthreads();

    // ---- epilogue: gather fp32 codebook rows, dwordx4 stores along hw
    {
        const int q  = t & 15;     // rows 4q..4q+3
        const int dg = t >> 4;     // 0..15 -> d in [dg*16, dg*16+16)
        const int c0i = sfin[4 * q + 0], c1i = sfin[4 * q + 1];
        const int c2i = sfin[4 * q + 2], c3i = sfin[4 * q + 3];
        const float* r0 = cb + c0i * DIM;
        const float* r1 = cb + c1i * DIM;
        const float* r2 = cb + c2i * DIM;
        const float* r3 = cb + c3i * DIM;
        float* ob = out + (size_t)batch * (DIM * 1024) + hw0 + 4 * q;
        #pragma unroll 4
        for (int j = 0; j < 16; ++j) {
            const int d = dg * 16 + j;
            f32x4_t v; v.x = r0[d]; v.y = r1[d]; v.z = r2[d]; v.w = r3[d];
            *(f32x4_t*)(ob + (size_t)d * 1024) = v;
        }
    }

    // ---- last block to finish computes the final loss (no vq_final dispatch)
    __threadfence();
    if (t == 0) {
        const unsigned old = atomicAdd(done, 1u);
        if (old == 1023u) {
            __threadfence();
            const float s = atomicAdd(loss_accum, 0.f);   // coherent read
            out[16777216] = 1.25f * s / 16777216.f;
        }
    }
}

extern "C" void kernel_launch(void* const* d_in, const int* in_sizes, int n_in,
                              void* d_out, int out_size, void* d_ws, size_t ws_size,
                              hipStream_t stream) {
    const float* x  = (const float*)d_in[0];   // [64,256,32,32]
    const float* cb = (const float*)d_in[1];   // [1024,256]
    float* out = (float*)d_out;                // 16777216 + 1

    char* ws = (char*)d_ws;
    float*    loss_accum = (float*)ws;                        // 4 B
    unsigned* done       = (unsigned*)(ws + 64);              // 4 B
    char*     cbsw       = ws + 1024;                         // 512 KB, A-frag order
    float*    nh_ord     = (float*)(ws + 1024 + 512 * 1024);  // 4 KB

    vq_prep<<<dim3(256), dim3(256), 0, stream>>>(cb, cbsw, nh_ord, loss_accum, done);
    vq_main<<<dim3(1024), dim3(256), 0, stream>>>(x, cb, (const bf16x8_t*)cbsw, nh_ord,
                                                  out, loss_accum, done);
}

// Round 5
// 163.109 us; speedup vs baseline: 1.9470x; 1.9470x over previous
//
#include <hip/hip_runtime.h>
#include <hip/hip_bf16.h>
#include <stdint.h>

// VectorQuantizer on MI355X (gfx950) — round 11
// inputs: x [64,256,32,32] fp32 (NCHW), codebook [1024,256] fp32
// outputs: q_st [64,256,32,32] fp32 (codebook[argmin] scattered back), loss scalar
//
// R11 = R6 (the 78 us vq_main local optimum) byte-identical EXCEPT ONE change:
// __launch_bounds__(256,3) -> (256,4). LDS 34.3 KB allows 4 blocks/CU (137 KB
// < 160 KB); grid 1024 = 4 x 256 CUs exactly. R6 uses 60 VGPR, far under both
// the old 170 and new 128 cap, so the allocator/scheduler should not change
// mode (R10's regression came from the 2x-accumulator split colliding with the
// budget, serializing the A-loads). Pure TLP experiment: 12 -> 16 waves/CU
// against an L2-latency-bound inner loop. R7/R8/R9/R10 all lost to R6 by
// perturbing its load schedule — this round perturbs nothing else.

#define DIM 256

typedef __attribute__((ext_vector_type(8)))  short bf16x8_t;   // MFMA A/B frag (4 VGPRs)
typedef __attribute__((ext_vector_type(4)))  float f32x4_t;
typedef __attribute__((ext_vector_type(16))) float f32x16_t;   // 32x32 C/D frag

__device__ __forceinline__ uint32_t f2bf(float f) {
    union { float f; uint32_t u; } v; v.f = f;
    uint32_t r = v.u + 0x7FFFu + ((v.u >> 16) & 1u);   // RNE
    return r >> 16;
}

// ---- prep: one wave per code. Emits (a) bf16 codebook in exact MFMA A-frag
// order: entry e=(mt*16+ks)*64+lane2 holds cb[mt*32+(lane2&31)][ks*16+(lane2>>5)*8+j],
// and (b) -0.5*||c||^2 in C/D-register order (nh_ord[mt*32 + half*16 + r]).
__global__ __launch_bounds__(256) void vq_prep(const float* __restrict__ cb,
                                               char* __restrict__ cbsw,
                                               float* __restrict__ nh_ord) {
    const int code = blockIdx.x * 4 + (threadIdx.x >> 6);
    const int l    = threadIdx.x & 63;               // holds d = 4l..4l+3
    const f32x4_t v = ((const f32x4_t*)(cb + code * DIM))[l];
    float sq = v.x * v.x + v.y * v.y + v.z * v.z + v.w * v.w;

    const int mt = code >> 5;
    const int ks = l >> 2;               // d/16
    const int hl = (l >> 1) & 1;         // (d%16)/8
    const uint32_t ebyte = (uint32_t)(((mt * 16 + ks) * 64 + (code & 31) + 32 * hl) * 16
                                      + (l & 1) * 8);
    uint2 o;
    o.x = f2bf(v.x) | (f2bf(v.y) << 16);
    o.y = f2bf(v.z) | (f2bf(v.w) << 16);
    *(uint2*)(cbsw + ebyte) = o;

    #pragma unroll
    for (int m = 32; m; m >>= 1) sq += __shfl_xor(sq, m);
    if (l == 0) {
        const int rw = code & 31;
        const int h4 = (rw >> 2) & 1;
        const int r  = (rw & 3) | ((rw >> 3) << 2);
        nh_ord[mt * 32 + h4 * 16 + r] = -0.5f * sq;
    }
}

// ---- main: 1024 blocks x 256 threads; block = 64 hw rows.
// LDS xt entry E=(ks*2+half)*64+row holds x[row][ks*16+half*8 .. +7] as 8 bf16 (16 B).
// Wave w: n-tile nt=w&1 (rows nt*32..), code-half ch=w>>1 (codes ch*512..).
__global__ __launch_bounds__(256, 4) void vq_main(const float* __restrict__ x,
                                                  const float* __restrict__ cb,
                                                  const bf16x8_t* __restrict__ cbsw,
                                                  const float* __restrict__ nh_ord,
                                                  float* __restrict__ out,
                                                  float* __restrict__ loss_accum) {
    __shared__ uint32_t xt[16 * 2 * 64 * 4];   // 32 KB, B-frag order
    __shared__ float smin[2][64];
    __shared__ int   sidx[2][64];
    __shared__ float sxsq[4];
    __shared__ int   sfin[64];

    const int t     = threadIdx.x;
    const int w     = t >> 6;
    const int lane  = t & 63;
    const int n0    = blockIdx.x * 64;
    const int batch = n0 >> 10;
    const int hw0   = n0 & 1023;

    // ---- stage x -> LDS in fragment order (conflict-free b128 writes) + ||x||^2
    {
        const int col = t & 63;          // hw row within block
        const int oct = t >> 6;          // 0..3: d-octet selector
        const float* xp = x + (size_t)batch * (DIM * 1024) + hw0 + col;
        float sq = 0.f;
        #pragma unroll
        for (int i = 0; i < 8; ++i) {
            const int d0 = oct * 8 + i * 32;     // 8 consecutive d, one LDS entry
            float a[8];
            #pragma unroll
            for (int j = 0; j < 8; ++j) {
                a[j] = xp[(size_t)(d0 + j) * 1024];
                sq += a[j] * a[j];
            }
            uint4 pk;
            pk.x = f2bf(a[0]) | (f2bf(a[1]) << 16);
            pk.y = f2bf(a[2]) | (f2bf(a[3]) << 16);
            pk.z = f2bf(a[4]) | (f2bf(a[5]) << 16);
            pk.w = f2bf(a[6]) | (f2bf(a[7]) << 16);
            const int ks   = d0 >> 4;
            const int half = (d0 >> 3) & 1;
            *(uint4*)&xt[(ks * 512) + (half * 256) + col * 4] = pk;
        }
        // wave-level ||x||^2 partial (all 256 threads cover every (row,d) once)
        #pragma unroll
        for (int m = 32; m; m >>= 1) sq += __shfl_xor(sq, m);
        if (lane == 0) sxsq[w] = sq;
    }
    __syncthreads();

    // ---- K-loop: wave's 512 codes (16 m-tiles); argmax(dot - 0.5*||c||^2)
    const int nt   = w & 1;
    const int ch   = w >> 1;
    const int half = lane >> 5;
    const int col  = lane & 31;
    const uint32_t* xbase = xt + half * 256 + (nt * 32 + col) * 4;

    float best = -3.0e38f;
    int   bi = 0;
    for (int i = 0; i < 16; ++i) {
        const int mt = ch * 16 + i;

        // batch-prefetch all 16 A-frags of this m-tile (16 independent
        // global_load_dwordx4 issued before any MFMA consumes them)
        bf16x8_t apre[16];
        {
            const bf16x8_t* ap = cbsw + mt * (16 * 64) + lane;
            #pragma unroll
            for (int ks = 0; ks < 16; ++ks) apre[ks] = ap[ks * 64];
        }

        const f32x4_t* nhp = (const f32x4_t*)(nh_ord + mt * 32 + half * 16);
        const f32x4_t h0 = nhp[0], h1 = nhp[1], h2 = nhp[2], h3 = nhp[3];
        f32x16_t acc;
        #pragma unroll
        for (int r = 0; r < 4; ++r) {
            acc[r] = h0[r]; acc[4 + r] = h1[r]; acc[8 + r] = h2[r]; acc[12 + r] = h3[r];
        }
        #pragma unroll
        for (int ks = 0; ks < 16; ++ks) {
            const bf16x8_t b = *(const bf16x8_t*)(xbase + ks * 512);
            acc = __builtin_amdgcn_mfma_f32_32x32x16_bf16(apre[ks], b, acc, 0, 0, 0);
        }
        #pragma unroll
        for (int r = 0; r < 16; ++r) {
            const int code = mt * 32 + half * 4 + ((r & 3) + 8 * (r >> 2));
            if (acc[r] > best) { best = acc[r]; bi = code; }
        }
    }

    // ---- combine the two k-half lanes (same hw row, disjoint code subsets)
    {
        const float ov = __shfl_xor(best, 32);
        const int   oi = __shfl_xor(bi, 32);
        if (ov > best || (ov == best && oi < bi)) { best = ov; bi = oi; }
    }
    if (lane < 32) {
        smin[ch][nt * 32 + lane] = best;
        sidx[ch][nt * 32 + lane] = bi;
    }
    __syncthreads();

    // ---- wave 0: combine code halves per row, loss partial, publish indices
    if (w == 0) {
        float b0 = smin[0][lane]; int i0 = sidx[0][lane];
        const float b1 = smin[1][lane]; const int i1 = sidx[1][lane];
        if (b1 > b0) { b0 = b1; i0 = i1; }
        sfin[lane] = i0;
        float ls = -2.f * b0;
        #pragma unroll
        for (int m = 32; m; m >>= 1) ls += __shfl_xor(ls, m);
        if (lane == 0)
            atomicAdd(loss_accum, ls + sxsq[0] + sxsq[1] + sxsq[2] + sxsq[3]);
    }
    __syncthreads();

    // ---- epilogue: gather fp32 codebook rows, dwordx4 stores along hw
    {
        const int q  = t & 15;     // rows 4q..4q+3
        const int dg = t >> 4;     // 0..15 -> d in [dg*16, dg*16+16)
        const int c0 = sfin[4 * q + 0], c1 = sfin[4 * q + 1];
        const int c2 = sfin[4 * q + 2], c3 = sfin[4 * q + 3];
        const float* r0 = cb + c0 * DIM;
        const float* r1 = cb + c1 * DIM;
        const float* r2 = cb + c2 * DIM;
        const float* r3 = cb + c3 * DIM;
        float* ob = out + (size_t)batch * (DIM * 1024) + hw0 + 4 * q;
        #pragma unroll 4
        for (int j = 0; j < 16; ++j) {
            const int d = dg * 16 + j;
            f32x4_t v; v.x = r0[d]; v.y = r1[d]; v.z = r2[d]; v.w = r3[d];
            *(f32x4_t*)(ob + (size_t)d * 1024) = v;
        }
    }
}

// ---- finalize loss ----
__global__ void vq_final(const float* __restrict__ loss_accum, float* __restrict__ out_loss) {
    *out_loss = 1.25f * (*loss_accum) / 16777216.f;
}

extern "C" void kernel_launch(void* const* d_in, const int* in_sizes, int n_in,
                              void* d_out, int out_size, void* d_ws, size_t ws_size,
                              hipStream_t stream) {
    const float* x  = (const float*)d_in[0];   // [64,256,32,32]
    const float* cb = (const float*)d_in[1];   // [1024,256]
    float* out = (float*)d_out;                // 16777216 + 1

    char* ws = (char*)d_ws;
    float* loss_accum = (float*)ws;                        // 4 B
    char*  cbsw       = ws + 1024;                         // 512 KB, A-frag order
    float* nh_ord     = (float*)(ws + 1024 + 512 * 1024);  // 4 KB

    hipMemsetAsync(loss_accum, 0, sizeof(float), stream);
    vq_prep<<<dim3(256), dim3(256), 0, stream>>>(cb, cbsw, nh_ord);
    vq_main<<<dim3(1024), dim3(256), 0, stream>>>(x, cb, (const bf16x8_t*)cbsw, nh_ord,
                                                  out, loss_accum);
    vq_final<<<dim3(1), dim3(1), 0, stream>>>(loss_accum, out + 16777216);
}